// Round 4
// baseline (64.239 us; speedup 1.0000x reference)
//
#include <hip/hip_runtime.h>

#define N 64
#define LC 64
#define LD 32
#define NCONT (N * N)

// Block-wide sum over 256 threads (4 waves). Result valid on thread 0.
__device__ inline float block_sum(float v, float* ws) {
    #pragma unroll
    for (int off = 32; off > 0; off >>= 1)
        v += __shfl_down(v, off, 64);
    const int lane = threadIdx.x & 63;
    const int wid  = threadIdx.x >> 6;
    __syncthreads();                 // safe reuse of ws
    if (lane == 0) ws[wid] = v;
    __syncthreads();
    return ws[0] + ws[1] + ws[2] + ws[3];
}

__global__ __launch_bounds__(256, 4) void loss_kernel(
    const float* __restrict__ cont_w,   // [N,N,LC]
    const float* __restrict__ disc_w,   // [N,N,LD]
    const float* __restrict__ gap_w,    // [N,N,LD]
    const int*   __restrict__ cont_gold,// [N,N] values 0..LC
    const int*   __restrict__ disc_gold,// [T]   values 0..LD
    const int*   __restrict__ cont_idx, // [T] row into (N*N, LD) disc table
    const int*   __restrict__ disc_idx, // [T] row into (N*N, LD) gap table
    float* __restrict__ partials,       // [gridDim.x]
    unsigned* __restrict__ counter,     // zeroed before launch
    float* __restrict__ out, int T)
{
    const int idx = blockIdx.x * blockDim.x + threadIdx.x;
    float acc = 0.0f;

    if (idx < NCONT) {
        // ---- continuous part: one cell per thread, upper triangle only ----
        const int i = idx >> 6, j = idx & 63;
        if (i <= j) {
            const float4* p = reinterpret_cast<const float4*>(cont_w + idx * LC);
            const int g = cont_gold[idx];            // 0..LC (LC == null col)
            const float goldv = (g < LC) ? cont_w[idx * LC + g] : 0.0f;
            float s0 = 1.0f, s1 = 0.0f, s2 = 0.0f, s3 = 0.0f;  // 1.0 = null col
            #pragma unroll
            for (int q = 0; q < LC / 4; ++q) {
                float4 x = p[q];
                s0 += __expf(x.x); s1 += __expf(x.y);
                s2 += __expf(x.z); s3 += __expf(x.w);
            }
            acc = __logf((s0 + s1) + (s2 + s3)) - goldv;
        }
    } else {
        // ---- discontinuous part: one tuple per thread ----
        const int t = idx - NCONT;
        if (t < T) {
            const int a = cont_idx[t];
            const int b = disc_idx[t];
            const int g = disc_gold[t];              // 0..LD (LD == null col)
            const float* ra = disc_w + a * LD;
            const float* rb = gap_w  + b * LD;
            const float4* pa = reinterpret_cast<const float4*>(ra);
            const float4* pb = reinterpret_cast<const float4*>(rb);
            // All row loads issued up-front -> one L2 round-trip in flight.
            float4 a0 = pa[0], a1 = pa[1], a2 = pa[2], a3 = pa[3];
            float4 a4 = pa[4], a5 = pa[5], a6 = pa[6], a7 = pa[7];
            float4 b0 = pb[0], b1 = pb[1], b2 = pb[2], b3 = pb[3];
            float4 b4 = pb[4], b5 = pb[5], b6 = pb[6], b7 = pb[7];
            // Gold via direct gather (lines already L1-hot) instead of 32 selects.
            float goldv = 0.0f;
            if (g < LD) goldv = ra[g] + rb[g];

            float s0 = 1.0f, s1 = 0.0f, s2 = 0.0f, s3 = 0.0f;  // 1.0 = null col
            #define DO4(xa, xb)                                            \
            {                                                              \
                s0 += __expf(xa.x + xb.x); s1 += __expf(xa.y + xb.y);      \
                s2 += __expf(xa.z + xb.z); s3 += __expf(xa.w + xb.w);      \
            }
            DO4(a0, b0) DO4(a1, b1) DO4(a2, b2) DO4(a3, b3)
            DO4(a4, b4) DO4(a5, b5) DO4(a6, b6) DO4(a7, b7)
            #undef DO4
            acc = __logf((s0 + s1) + (s2 + s3)) - goldv;
        }
    }

    __shared__ float ws[4];
    __shared__ bool  is_last;
    const float bsum = block_sum(acc, ws);

    // ---- threadfence reduction: last-arriving block does the final sum ----
    if (threadIdx.x == 0) {
        partials[blockIdx.x] = bsum;
        __threadfence();                         // release partials device-wide
        const unsigned r = atomicAdd(counter, 1u);
        is_last = (r == gridDim.x - 1);
    }
    __syncthreads();
    if (is_last) {
        __threadfence();                         // acquire others' partials
        float s = 0.0f;
        for (int i = threadIdx.x; i < (int)gridDim.x; i += blockDim.x)
            s += partials[i];                    // fixed order -> deterministic
        const float tot = block_sum(s, ws);
        if (threadIdx.x == 0) out[0] = tot;
    }
}

extern "C" void kernel_launch(void* const* d_in, const int* in_sizes, int n_in,
                              void* d_out, int out_size, void* d_ws, size_t ws_size,
                              hipStream_t stream) {
    const float* cont_w    = (const float*)d_in[0];
    const float* disc_w    = (const float*)d_in[1];
    const float* gap_w     = (const float*)d_in[2];
    const int*   cont_gold = (const int*)d_in[3];
    const int*   disc_gold = (const int*)d_in[4];
    const int*   cont_idx  = (const int*)d_in[5];
    const int*   disc_idx  = (const int*)d_in[6];
    float* out = (float*)d_out;
    const int T = in_sizes[4];

    unsigned* counter = (unsigned*)d_ws;                    // 4 bytes
    float*    partials = (float*)((char*)d_ws + 256);       // [blocks]

    hipMemsetAsync(counter, 0, sizeof(unsigned), stream);

    const int total  = NCONT + T;
    const int blocks = (total + 255) / 256;
    loss_kernel<<<blocks, 256, 0, stream>>>(cont_w, disc_w, gap_w, cont_gold,
                                            disc_gold, cont_idx, disc_idx,
                                            partials, counter, out, T);
}

// Round 5
// 17.729 us; speedup vs baseline: 3.6234x; 3.6234x over previous
//
#include <hip/hip_runtime.h>

#define N 64
#define LC 64
#define LD 32
#define NCONT (N * N)
#define CONT_BLOCKS 16          // 16 * 256 = 4096 cells
#define TUP_PER_GROUP 4         // tuples per 8-lane group
#define TUP_PER_BLOCK 128       // 32 groups * 4

// Block-wide sum over 256 threads (4 waves). Result valid on thread 0.
__device__ inline float block_sum(float v, float* ws) {
    #pragma unroll
    for (int off = 32; off > 0; off >>= 1)
        v += __shfl_down(v, off, 64);
    const int lane = threadIdx.x & 63;
    const int wid  = threadIdx.x >> 6;
    if (lane == 0) ws[wid] = v;
    __syncthreads();
    return ws[0] + ws[1] + ws[2] + ws[3];
}

__global__ __launch_bounds__(256, 4) void loss_kernel(
    const float* __restrict__ cont_w,   // [N,N,LC]
    const float* __restrict__ disc_w,   // [N,N,LD]
    const float* __restrict__ gap_w,    // [N,N,LD]
    const int*   __restrict__ cont_gold,// [N,N] values 0..LC
    const int*   __restrict__ disc_gold,// [T]   values 0..LD
    const int*   __restrict__ cont_idx, // [T] row into (N*N, LD) disc table
    const int*   __restrict__ disc_idx, // [T] row into (N*N, LD) gap table
    float* __restrict__ partials, int T)
{
    float acc = 0.0f;

    if (blockIdx.x < CONT_BLOCKS) {
        // ---- continuous part: one cell per thread, upper triangle only ----
        const int idx = blockIdx.x * 256 + threadIdx.x;   // 0..4095
        const int i = idx >> 6, j = idx & 63;
        if (i <= j) {
            const float4* p = reinterpret_cast<const float4*>(cont_w + idx * LC);
            const int g = cont_gold[idx];            // 0..LC (LC == null col)
            const float goldv = (g < LC) ? cont_w[idx * LC + g] : 0.0f;
            float s0 = 1.0f, s1 = 0.0f, s2 = 0.0f, s3 = 0.0f;  // 1.0 = null col
            #pragma unroll
            for (int q = 0; q < LC / 4; ++q) {
                float4 x = p[q];
                s0 += __expf(x.x); s1 += __expf(x.y);
                s2 += __expf(x.z); s3 += __expf(x.w);
            }
            acc = __logf((s0 + s1) + (s2 + s3)) - goldv;
        }
    } else {
        // ---- discontinuous part: 8 lanes cooperate on each tuple ----
        // lane q of a group loads float4 #q (columns 4q..4q+3) of both rows:
        // consecutive lane quartets hit the SAME 64B line -> low address
        // divergence per load instruction (16 lines/instr, not 64).
        const int lane8 = threadIdx.x & 7;            // chunk id 0..7
        const int group = threadIdx.x >> 3;           // 0..31 in block
        const int t0 = (blockIdx.x - CONT_BLOCKS) * TUP_PER_BLOCK
                     + group * TUP_PER_GROUP;
        if (t0 < T) {
            // T % 4 == 0, so a live group always has 4 valid tuples.
            const int4 c4 = *reinterpret_cast<const int4*>(cont_idx + t0);
            const int4 d4 = *reinterpret_cast<const int4*>(disc_idx + t0);
            const int4 g4 = *reinterpret_cast<const int4*>(disc_gold + t0);
            const int ci[4] = {c4.x, c4.y, c4.z, c4.w};
            const int di[4] = {d4.x, d4.y, d4.z, d4.w};
            const int gi[4] = {g4.x, g4.y, g4.z, g4.w};

            // Issue all 8 gather loads before consuming any.
            float4 va[TUP_PER_GROUP], vb[TUP_PER_GROUP];
            #pragma unroll
            for (int u = 0; u < TUP_PER_GROUP; ++u) {
                va[u] = *reinterpret_cast<const float4*>(
                            disc_w + ci[u] * LD + lane8 * 4);
                vb[u] = *reinterpret_cast<const float4*>(
                            gap_w + di[u] * LD + lane8 * 4);
            }
            #pragma unroll
            for (int u = 0; u < TUP_PER_GROUP; ++u) {
                const float v0 = va[u].x + vb[u].x;
                const float v1 = va[u].y + vb[u].y;
                const float v2 = va[u].z + vb[u].z;
                const float v3 = va[u].w + vb[u].w;
                float s = (__expf(v0) + __expf(v1)) + (__expf(v2) + __expf(v3));
                const int g = gi[u];                  // 0..32 (32 == null col)
                float gv = 0.0f;
                if ((g >> 2) == lane8)                // g==32 -> 8, never matches
                    gv = (g & 2) ? ((g & 1) ? v3 : v2) : ((g & 1) ? v1 : v0);
                // 8-lane tree reduce of (s, gv)
                s  += __shfl_xor(s, 1, 64);  gv += __shfl_xor(gv, 1, 64);
                s  += __shfl_xor(s, 2, 64);  gv += __shfl_xor(gv, 2, 64);
                s  += __shfl_xor(s, 4, 64);  gv += __shfl_xor(gv, 4, 64);
                if (lane8 == 0)
                    acc += __logf(s + 1.0f) - gv;     // +1.0 = null column
            }
        }
    }

    __shared__ float ws[4];
    const float bsum = block_sum(acc, ws);
    if (threadIdx.x == 0)
        partials[blockIdx.x] = bsum;                  // NO atomics, NO fences
}

__global__ __launch_bounds__(1024) void reduce_kernel(
    const float* __restrict__ partials, float* __restrict__ out, int nblocks)
{
    float acc = 0.0f;
    for (int i = threadIdx.x; i < nblocks; i += 1024)
        acc += partials[i];
    #pragma unroll
    for (int off = 32; off > 0; off >>= 1)
        acc += __shfl_down(acc, off, 64);

    __shared__ float ws[16];
    const int lane = threadIdx.x & 63;
    const int wid  = threadIdx.x >> 6;
    if (lane == 0) ws[wid] = acc;
    __syncthreads();
    if (threadIdx.x == 0) {
        float s = 0.0f;
        #pragma unroll
        for (int w = 0; w < 16; ++w) s += ws[w];
        out[0] = s;
    }
}

extern "C" void kernel_launch(void* const* d_in, const int* in_sizes, int n_in,
                              void* d_out, int out_size, void* d_ws, size_t ws_size,
                              hipStream_t stream) {
    const float* cont_w    = (const float*)d_in[0];
    const float* disc_w    = (const float*)d_in[1];
    const float* gap_w     = (const float*)d_in[2];
    const int*   cont_gold = (const int*)d_in[3];
    const int*   disc_gold = (const int*)d_in[4];
    const int*   cont_idx  = (const int*)d_in[5];
    const int*   disc_idx  = (const int*)d_in[6];
    float* out      = (float*)d_out;
    float* partials = (float*)d_ws;
    const int T = in_sizes[4];

    const int disc_blocks = (T + TUP_PER_BLOCK - 1) / TUP_PER_BLOCK;
    const int blocks = CONT_BLOCKS + disc_blocks;
    loss_kernel<<<blocks, 256, 0, stream>>>(cont_w, disc_w, gap_w, cont_gold,
                                            disc_gold, cont_idx, disc_idx,
                                            partials, T);
    reduce_kernel<<<1, 1024, 0, stream>>>(partials, out, blocks);
}